// Round 2
// baseline (237.271 us; speedup 1.0000x reference)
//
#include <hip/hip_runtime.h>

// S=8192, H=2048
// energies[s] = enc[s,:] . (W^T h)   (the +b.h term is constant across s ->
//                                     softmax-invariant, dropped)
// out = softmax(energies)
// ws floats: part[128*2048] | v[2048] | e[8192] | cnt(uint)

#define Hdim 2048
#define Sdim 8192
#define PCHUNKS 128
#define PROWS 16  // Hdim / PCHUNKS

__global__ void k1_partial(const float* __restrict__ W, const float* __restrict__ hid,
                           float* __restrict__ part) {
    // grid (2, 128), block 256. Thread: 4 consecutive cols, 16 rows.
    int t = threadIdx.x;
    int colBase = blockIdx.x * 1024 + t * 4;
    int k0 = blockIdx.y * PROWS;
    float4 acc = {0.f, 0.f, 0.f, 0.f};
#pragma unroll
    for (int i = 0; i < PROWS; ++i) {
        int k = k0 + i;
        float hk = hid[k];
        float4 w = *reinterpret_cast<const float4*>(W + (size_t)k * Hdim + colBase);
        acc.x += w.x * hk;
        acc.y += w.y * hk;
        acc.z += w.z * hk;
        acc.w += w.w * hk;
    }
    *reinterpret_cast<float4*>(part + (size_t)blockIdx.y * Hdim + colBase) = acc;
}

__global__ void k1b_reduce(const float* __restrict__ part, float* __restrict__ v,
                           unsigned int* __restrict__ cnt) {
    // 32 blocks x 256 thr. Block owns 64 cols; 4 thread-groups each sum 32 partials.
    __shared__ float red[256];
    int t = threadIdx.x;
    int col = blockIdx.x * 64 + (t & 63);
    int j0 = (t >> 6) * 32;
    float s = 0.f;
#pragma unroll
    for (int j = 0; j < 32; ++j) s += part[(size_t)(j0 + j) * Hdim + col];
    red[t] = s;
    __syncthreads();
    if (t < 64) v[col] = red[t] + red[64 + t] + red[128 + t] + red[192 + t];
    if (blockIdx.x == 0 && t == 0) *cnt = 0;  // reset fusion counter every call
}

__global__ void k2_energies_softmax(const float* __restrict__ enc, const float* __restrict__ v,
                                    float* __restrict__ e, unsigned int* __restrict__ cnt,
                                    float* __restrict__ out) {
    // 2048 blocks x 256 thr; 4 waves/block, one enc row per wave.
    int t = threadIdx.x;
    int wave = t >> 6;
    int lane = t & 63;
    int s = blockIdx.x * 4 + wave;
    const float* row = enc + (size_t)s * Hdim;
    float acc = 0.f;
#pragma unroll
    for (int i = 0; i < 8; ++i) {
        int idx = i * 256 + lane * 4;
        float4 a = *reinterpret_cast<const float4*>(row + idx);
        float4 w = *reinterpret_cast<const float4*>(v + idx);
        acc += a.x * w.x + a.y * w.y + a.z * w.z + a.w * w.w;
    }
#pragma unroll
    for (int off = 32; off > 0; off >>= 1) acc += __shfl_xor(acc, off, 64);
    if (lane == 0) e[s] = acc;

    // ---- last-block-done softmax over all 8192 energies ----
    __shared__ bool amLast;
    __threadfence();  // make e[] visible device-wide before signaling
    if (t == 0) amLast = (atomicAdd(cnt, 1u) == gridDim.x - 1);
    __syncthreads();
    if (!amLast) return;
    __threadfence();  // acquire: all other blocks' e[] stores

    __shared__ float red[4];
    __shared__ float bcast;
    // 256 threads x 32 elems each, float4-coalesced
    float vals[32];
#pragma unroll
    for (int i = 0; i < 8; ++i) {
        float4 a = *reinterpret_cast<const float4*>(e + i * 1024 + t * 4);
        vals[i * 4 + 0] = a.x;
        vals[i * 4 + 1] = a.y;
        vals[i * 4 + 2] = a.z;
        vals[i * 4 + 3] = a.w;
    }
    float m = vals[0];
#pragma unroll
    for (int i = 1; i < 32; ++i) m = fmaxf(m, vals[i]);
#pragma unroll
    for (int off = 32; off > 0; off >>= 1) m = fmaxf(m, __shfl_xor(m, off, 64));
    if (lane == 0) red[wave] = m;
    __syncthreads();
    if (t == 0) bcast = fmaxf(fmaxf(red[0], red[1]), fmaxf(red[2], red[3]));
    __syncthreads();
    m = bcast;
    float ssum = 0.f;
#pragma unroll
    for (int i = 0; i < 32; ++i) {
        vals[i] = __expf(vals[i] - m);
        ssum += vals[i];
    }
#pragma unroll
    for (int off = 32; off > 0; off >>= 1) ssum += __shfl_xor(ssum, off, 64);
    __syncthreads();
    if (lane == 0) red[wave] = ssum;
    __syncthreads();
    if (t == 0) bcast = red[0] + red[1] + red[2] + red[3];
    __syncthreads();
    float inv = 1.0f / bcast;
#pragma unroll
    for (int i = 0; i < 8; ++i) {
        float4 o = {vals[i * 4 + 0] * inv, vals[i * 4 + 1] * inv,
                    vals[i * 4 + 2] * inv, vals[i * 4 + 3] * inv};
        *reinterpret_cast<float4*>(out + i * 1024 + t * 4) = o;
    }
}

extern "C" void kernel_launch(void* const* d_in, const int* in_sizes, int n_in,
                              void* d_out, int out_size, void* d_ws, size_t ws_size,
                              hipStream_t stream) {
    const float* hid = (const float*)d_in[0];   // (1, H)
    const float* enc = (const float*)d_in[1];   // (S, 1, H)
    const float* W   = (const float*)d_in[2];   // (H, H)
    // d_in[3] = b : dropped (softmax shift-invariant)
    float* out = (float*)d_out;                 // S floats
    float* ws = (float*)d_ws;

    float* part = ws;                              // 128*2048
    float* v    = part + PCHUNKS * Hdim;           // 2048
    float* e    = v + Hdim;                        // 8192
    unsigned int* cnt = (unsigned int*)(e + Sdim); // 1

    k1_partial<<<dim3(2, PCHUNKS), 256, 0, stream>>>(W, hid, part);
    k1b_reduce<<<32, 256, 0, stream>>>(part, v, cnt);
    k2_energies_softmax<<<Sdim / 4, 256, 0, stream>>>(enc, v, e, cnt, out);
}

// Round 3
// 26.519 us; speedup vs baseline: 8.9472x; 8.9472x over previous
//
#include <hip/hip_runtime.h>

// S=8192, H=2048
// energies[s] = enc[s,:] . (W^T h)   (+b.h is constant across s -> softmax-invariant, dropped)
// out = softmax(energies)
// ws floats: part[128*2048] | v[2048] | e[8192]

#define Hdim 2048
#define Sdim 8192
#define PCHUNKS 128
#define PROWS 16  // Hdim / PCHUNKS

__global__ void k1_partial(const float* __restrict__ W, const float* __restrict__ hid,
                           float* __restrict__ part) {
    // grid (2, 128), block 256 -> 256 blocks (1/CU). Thread: 4 consecutive cols, 16 rows.
    int t = threadIdx.x;
    int colBase = blockIdx.x * 1024 + t * 4;
    int k0 = blockIdx.y * PROWS;
    float4 acc = {0.f, 0.f, 0.f, 0.f};
#pragma unroll
    for (int i = 0; i < PROWS; ++i) {
        int k = k0 + i;
        float hk = hid[k];
        float4 w = *reinterpret_cast<const float4*>(W + (size_t)k * Hdim + colBase);
        acc.x += w.x * hk;
        acc.y += w.y * hk;
        acc.z += w.z * hk;
        acc.w += w.w * hk;
    }
    *reinterpret_cast<float4*>(part + (size_t)blockIdx.y * Hdim + colBase) = acc;
}

__global__ void k1b_reduce(const float* __restrict__ part, float* __restrict__ v) {
    // 32 blocks x 256 thr. Block owns 64 cols; 4 thread-groups each sum 32 partials.
    __shared__ float red[256];
    int t = threadIdx.x;
    int col = blockIdx.x * 64 + (t & 63);
    int j0 = (t >> 6) * 32;
    float s = 0.f;
#pragma unroll
    for (int j = 0; j < 32; ++j) s += part[(size_t)(j0 + j) * Hdim + col];
    red[t] = s;
    __syncthreads();
    if (t < 64) v[col] = red[t] + red[64 + t] + red[128 + t] + red[192 + t];
}

__global__ void k2_energies(const float* __restrict__ enc, const float* __restrict__ v,
                            float* __restrict__ e) {
    // 2048 blocks x 256 thr; 4 waves/block, one enc row per wave. 8 x float4 per lane.
    int t = threadIdx.x;
    int lane = t & 63;
    int s = blockIdx.x * 4 + (t >> 6);
    const float* row = enc + (size_t)s * Hdim;
    float acc = 0.f;
#pragma unroll
    for (int i = 0; i < 8; ++i) {
        int idx = i * 256 + lane * 4;
        float4 a = *reinterpret_cast<const float4*>(row + idx);
        float4 w = *reinterpret_cast<const float4*>(v + idx);
        acc += a.x * w.x + a.y * w.y + a.z * w.z + a.w * w.w;
    }
#pragma unroll
    for (int off = 32; off > 0; off >>= 1) acc += __shfl_xor(acc, off, 64);
    if (lane == 0) e[s] = acc;
}

__global__ void k3_softmax(const float* __restrict__ e, float* __restrict__ out) {
    // 1 block, 1024 threads, 8 elems each.
    __shared__ float red[16];
    __shared__ float bcast;
    int t = threadIdx.x;
    int lane = t & 63, wid = t >> 6;
    float4 a = *reinterpret_cast<const float4*>(e + t * 8);
    float4 bq = *reinterpret_cast<const float4*>(e + t * 8 + 4);
    float vals[8] = {a.x, a.y, a.z, a.w, bq.x, bq.y, bq.z, bq.w};
    float m = vals[0];
#pragma unroll
    for (int i = 1; i < 8; ++i) m = fmaxf(m, vals[i]);
#pragma unroll
    for (int off = 32; off > 0; off >>= 1) m = fmaxf(m, __shfl_xor(m, off, 64));
    if (lane == 0) red[wid] = m;
    __syncthreads();
    if (wid == 0) {
        float mm = (lane < 16) ? red[lane] : -1e30f;
#pragma unroll
        for (int off = 8; off > 0; off >>= 1) mm = fmaxf(mm, __shfl_xor(mm, off, 64));
        if (lane == 0) bcast = mm;
    }
    __syncthreads();
    m = bcast;
    float ex[8];
    float s = 0.f;
#pragma unroll
    for (int i = 0; i < 8; ++i) {
        ex[i] = __expf(vals[i] - m);
        s += ex[i];
    }
#pragma unroll
    for (int off = 32; off > 0; off >>= 1) s += __shfl_xor(s, off, 64);
    __syncthreads();
    if (lane == 0) red[wid] = s;
    __syncthreads();
    if (wid == 0) {
        float ss = (lane < 16) ? red[lane] : 0.f;
#pragma unroll
        for (int off = 8; off > 0; off >>= 1) ss += __shfl_xor(ss, off, 64);
        if (lane == 0) bcast = ss;
    }
    __syncthreads();
    float inv = 1.0f / bcast;
    float4 o1 = {ex[0] * inv, ex[1] * inv, ex[2] * inv, ex[3] * inv};
    float4 o2 = {ex[4] * inv, ex[5] * inv, ex[6] * inv, ex[7] * inv};
    *reinterpret_cast<float4*>(out + t * 8) = o1;
    *reinterpret_cast<float4*>(out + t * 8 + 4) = o2;
}

extern "C" void kernel_launch(void* const* d_in, const int* in_sizes, int n_in,
                              void* d_out, int out_size, void* d_ws, size_t ws_size,
                              hipStream_t stream) {
    const float* hid = (const float*)d_in[0];   // (1, H)
    const float* enc = (const float*)d_in[1];   // (S, 1, H)
    const float* W   = (const float*)d_in[2];   // (H, H)
    // d_in[3] = b : dropped (softmax shift-invariant)
    float* out = (float*)d_out;                 // S floats
    float* ws = (float*)d_ws;

    float* part = ws;                        // 128*2048
    float* v    = part + PCHUNKS * Hdim;     // 2048
    float* e    = v + Hdim;                  // 8192

    k1_partial<<<dim3(2, PCHUNKS), 256, 0, stream>>>(W, hid, part);
    k1b_reduce<<<32, 256, 0, stream>>>(part, v);
    k2_energies<<<Sdim / 4, 256, 0, stream>>>(enc, v, e);
    k3_softmax<<<1, 1024, 0, stream>>>(e, out);
}

// Round 5
// 23.628 us; speedup vs baseline: 10.0418x; 1.1223x over previous
//
#include <hip/hip_runtime.h>

// S=8192, H=2048
// v = W^T h;  energies[s] = enc[s,:] . v  (+b.h softmax-invariant, dropped)
// out = softmax(energies)
// ws floats: v[2048] | e[8192]

#define Hdim 2048
#define Sdim 8192

typedef float vfloat4 __attribute__((ext_vector_type(4)));

__global__ void kv_matvec(const float* __restrict__ W, const float* __restrict__ hid,
                          float* __restrict__ v) {
    // 256 blocks x 512 thr. Block owns 8 columns, all 2048 rows -> v written directly.
    // XCD swizzle: hardware round-robins blockIdx across 8 XCDs (b&7 = XCD).
    // Give XCD x the contiguous columns [x*256, x*256+256) so the 4 blocks that
    // share each 128B line of W sit on the SAME XCD L2 (line fetched once).
    int b = blockIdx.x;
    int c0 = (b & 7) * 256 + (b >> 3) * 8;  // 8 cols for this block
    int t = threadIdx.x;                     // 0..511
    int cp = (t & 1) * 4;                    // which float4 of the 8 cols
    int rl = t >> 1;                         // 0..255 row lane
    float4 acc = {0.f, 0.f, 0.f, 0.f};
#pragma unroll
    for (int i = 0; i < 8; ++i) {
        int k = rl + 256 * i;
        float hk = hid[k];
        float4 w = *reinterpret_cast<const float4*>(W + (size_t)k * Hdim + c0 + cp);
        acc.x += w.x * hk;
        acc.y += w.y * hk;
        acc.z += w.z * hk;
        acc.w += w.w * hk;
    }
    __shared__ float4 red[512];
    red[t] = acc;
    __syncthreads();
    for (int s = 128; s > 0; s >>= 1) {
        if (rl < s) {
            float4 o = red[t + 2 * s];
            float4 m = red[t];
            m.x += o.x; m.y += o.y; m.z += o.z; m.w += o.w;
            red[t] = m;
        }
        __syncthreads();
    }
    if (t < 2) *reinterpret_cast<float4*>(v + c0 + t * 4) = red[t];
}

__global__ void k2_energies(const float* __restrict__ enc, const float* __restrict__ v,
                            float* __restrict__ e) {
    // 2048 blocks x 256 thr; 4 waves/block, one enc row per wave. 8 x float4 per lane.
    int t = threadIdx.x;
    int lane = t & 63;
    int s = blockIdx.x * 4 + (t >> 6);
    const float* row = enc + (size_t)s * Hdim;
    float acc = 0.f;
#pragma unroll
    for (int i = 0; i < 8; ++i) {
        int idx = i * 256 + lane * 4;
        vfloat4 a = __builtin_nontemporal_load(reinterpret_cast<const vfloat4*>(row + idx));
        float4 w = *reinterpret_cast<const float4*>(v + idx);
        acc += a.x * w.x + a.y * w.y + a.z * w.z + a.w * w.w;
    }
#pragma unroll
    for (int off = 32; off > 0; off >>= 1) acc += __shfl_xor(acc, off, 64);
    if (lane == 0) e[s] = acc;
}

__global__ void k3_softmax(const float* __restrict__ e, float* __restrict__ out) {
    // 1 block, 1024 threads, 8 elems each.
    __shared__ float red[16];
    __shared__ float bcast;
    int t = threadIdx.x;
    int lane = t & 63, wid = t >> 6;
    float4 a = *reinterpret_cast<const float4*>(e + t * 8);
    float4 bq = *reinterpret_cast<const float4*>(e + t * 8 + 4);
    float vals[8] = {a.x, a.y, a.z, a.w, bq.x, bq.y, bq.z, bq.w};
    float m = vals[0];
#pragma unroll
    for (int i = 1; i < 8; ++i) m = fmaxf(m, vals[i]);
#pragma unroll
    for (int off = 32; off > 0; off >>= 1) m = fmaxf(m, __shfl_xor(m, off, 64));
    if (lane == 0) red[wid] = m;
    __syncthreads();
    if (wid == 0) {
        float mm = (lane < 16) ? red[lane] : -1e30f;
#pragma unroll
        for (int off = 8; off > 0; off >>= 1) mm = fmaxf(mm, __shfl_xor(mm, off, 64));
        if (lane == 0) bcast = mm;
    }
    __syncthreads();
    m = bcast;
    float ex[8];
    float s = 0.f;
#pragma unroll
    for (int i = 0; i < 8; ++i) {
        ex[i] = __expf(vals[i] - m);
        s += ex[i];
    }
#pragma unroll
    for (int off = 32; off > 0; off >>= 1) s += __shfl_xor(s, off, 64);
    __syncthreads();
    if (lane == 0) red[wid] = s;
    __syncthreads();
    if (wid == 0) {
        float ss = (lane < 16) ? red[lane] : 0.f;
#pragma unroll
        for (int off = 8; off > 0; off >>= 1) ss += __shfl_xor(ss, off, 64);
        if (lane == 0) bcast = ss;
    }
    __syncthreads();
    float inv = 1.0f / bcast;
    float4 o1 = {ex[0] * inv, ex[1] * inv, ex[2] * inv, ex[3] * inv};
    float4 o2 = {ex[4] * inv, ex[5] * inv, ex[6] * inv, ex[7] * inv};
    *reinterpret_cast<float4*>(out + t * 8) = o1;
    *reinterpret_cast<float4*>(out + t * 8 + 4) = o2;
}

extern "C" void kernel_launch(void* const* d_in, const int* in_sizes, int n_in,
                              void* d_out, int out_size, void* d_ws, size_t ws_size,
                              hipStream_t stream) {
    const float* hid = (const float*)d_in[0];   // (1, H)
    const float* enc = (const float*)d_in[1];   // (S, 1, H)
    const float* W   = (const float*)d_in[2];   // (H, H)
    // d_in[3] = b : dropped (softmax shift-invariant)
    float* out = (float*)d_out;                 // S floats
    float* ws = (float*)d_ws;

    float* v = ws;            // 2048
    float* e = v + Hdim;      // 8192

    kv_matvec<<<256, 512, 0, stream>>>(W, hid, v);
    k2_energies<<<Sdim / 4, 256, 0, stream>>>(enc, v, e);
    k3_softmax<<<1, 1024, 0, stream>>>(e, out);
}